// Round 17
// baseline (118.149 us; speedup 1.0000x reference)
//
#include <hip/hip_runtime.h>
#include <math.h>

#define N1 50000
#define N2 50000
#define NE 640000
#define D 128
#define AD 64
#define CAP 64          // bucket capacity; Poisson(12.8) => P(deg>64) ~ 1e-17
#define EPSN 1e-8f

#define CONV_BLKS ((N2 + 31) / 32)   // 1563 (32 rows/block, 8 lanes/row)
#define FILL_BLKS (NE / 256)         // 2500
#define GATE_BLKS ((N1 + 63) / 64)   // 782

typedef _Float16 half2_t __attribute__((ext_vector_type(2)));

__device__ __forceinline__ half2_t pkh(float a, float b) {
    return __builtin_bit_cast(half2_t, __builtin_amdgcn_cvt_pkrtz(a, b));
}
__device__ __forceinline__ unsigned h2u(half2_t h) { return __builtin_bit_cast(unsigned, h); }
__device__ __forceinline__ half2_t u2h(unsigned u) { return __builtin_bit_cast(half2_t, u); }

// ---- conv: Wg transpose | X2->f16+inv2 (4 loads deep) | zero deg --------
// Pure streaming kernel — scatters/atomics live in fill_kernel (R15 lesson:
// merging streaming stores with random atomics serializes both).
__global__ __launch_bounds__(256) void conv_kernel(const float* __restrict__ Wg,
                                                   float2* __restrict__ WgT2g,
                                                   const float* __restrict__ X2,
                                                   uint4* __restrict__ X2h,
                                                   float* __restrict__ inv2,
                                                   int* __restrict__ deg) {
    int bid = blockIdx.x;
    int tid = threadIdx.x;
    if (bid < 16) {
        // WgT2g[k*64+j2] = (Wg[2j2][k], Wg[2j2+1][k]); Wg is [D][AD] row-major
        int t = bid * 256 + tid;
        int k = t >> 6, j2 = t & 63;
        WgT2g[t] = make_float2(Wg[(size_t)(2 * j2) * AD + k],
                               Wg[(size_t)(2 * j2 + 1) * AD + k]);
        return;
    }
    int rbase = (bid - 16) * 32;
    if (tid < 32 && rbase + tid < N1) deg[rbase + tid] = 0;  // replaces memset
    int row = rbase + (tid >> 3);
    if (row >= N2) return;
    int l8 = tid & 7;  // lane covers floats 16*l8 .. 16*l8+15
    const float4* pr = (const float4*)(X2 + (size_t)row * D) + l8 * 4;
    float4 v0 = pr[0], v1 = pr[1], v2 = pr[2], v3 = pr[3];
    float s = v0.x * v0.x + v0.y * v0.y + v0.z * v0.z + v0.w * v0.w
            + v1.x * v1.x + v1.y * v1.y + v1.z * v1.z + v1.w * v1.w
            + v2.x * v2.x + v2.y * v2.y + v2.z * v2.z + v2.w * v2.w
            + v3.x * v3.x + v3.y * v3.y + v3.z * v3.z + v3.w * v3.w;
    s += __shfl_xor(s, 4);
    s += __shfl_xor(s, 2);
    s += __shfl_xor(s, 1);
    if (l8 == 0) inv2[row] = 1.0f / fmaxf(sqrtf(s), EPSN);
    uint4 w0 = make_uint4(h2u(pkh(v0.x, v0.y)), h2u(pkh(v0.z, v0.w)),
                          h2u(pkh(v1.x, v1.y)), h2u(pkh(v1.z, v1.w)));
    uint4 w1 = make_uint4(h2u(pkh(v2.x, v2.y)), h2u(pkh(v2.z, v2.w)),
                          h2u(pkh(v3.x, v3.y)), h2u(pkh(v3.z, v3.w)));
    uint4* dstp = X2h + (size_t)row * 16 + l8 * 2;
    dstp[0] = w0;
    dstp[1] = w1;
}

// ---- fill: bucket scatter (standalone — atomic/scatter-bound) -----------
__global__ void fill_kernel(const int* __restrict__ src, const int* __restrict__ dst,
                            int* __restrict__ deg, int* __restrict__ cdst) {
    int e = blockIdx.x * blockDim.x + threadIdx.x;  // 2500*256 == NE exactly
    int s = src[e];
    int p = atomicAdd(deg + s, 1);
    if (p < CAP) cdst[(size_t)s * CAP + p] = dst[e];
}

// ---- gates: sigmoid(Xn @ Wg^T) -> f16 ws buffer -------------------------
// Register-tiled; node index wave-uniform (readfirstlane) -> Xn loads go
// through the scalar path. WgT2g staged coalesced into LDS (conflict-free).
__global__ __launch_bounds__(256) void gate_kernel(const float* __restrict__ Xn,
                                                   const float2* __restrict__ WgT2g,
                                                   unsigned* __restrict__ gates) {
    __shared__ float2 WgT2[AD * 64];  // 32 KB
    for (int t = threadIdx.x; t < AD * 64; t += 256) WgT2[t] = WgT2g[t];
    __syncthreads();

    int j2 = threadIdx.x & 63;  // lane: output columns (2*j2, 2*j2+1)
    int slot = __builtin_amdgcn_readfirstlane(threadIdx.x >> 6);
    int base = blockIdx.x * 64 + slot * 16;

    #pragma unroll
    for (int g = 0; g < 4; ++g) {
        int n0 = base + g * 4;
        if (n0 >= N1) break;  // wave-uniform tail guard
        const float* x0 = Xn + (size_t)n0 * AD;
        const float* x1 = x0 + AD;
        const float* x2 = x0 + 2 * AD;
        const float* x3 = x0 + 3 * AD;
        float a00 = 0.f, a01 = 0.f, a10 = 0.f, a11 = 0.f;
        float a20 = 0.f, a21 = 0.f, a30 = 0.f, a31 = 0.f;
        #pragma unroll
        for (int k = 0; k < AD; ++k) {
            float2 w = WgT2[k * 64 + j2];
            float v0 = x0[k], v1 = x1[k], v2 = x2[k], v3 = x3[k];
            a00 += v0 * w.x; a01 += v0 * w.y;
            a10 += v1 * w.x; a11 += v1 * w.y;
            a20 += v2 * w.x; a21 += v2 * w.y;
            a30 += v3 * w.x; a31 += v3 * w.y;
        }
        float g00 = 1.0f / (1.0f + __expf(-a00));
        float g01 = 1.0f / (1.0f + __expf(-a01));
        float g10 = 1.0f / (1.0f + __expf(-a10));
        float g11 = 1.0f / (1.0f + __expf(-a11));
        float g20 = 1.0f / (1.0f + __expf(-a20));
        float g21 = 1.0f / (1.0f + __expf(-a21));
        float g30 = 1.0f / (1.0f + __expf(-a30));
        float g31 = 1.0f / (1.0f + __expf(-a31));
        gates[(size_t)n0 * 64 + j2]       = h2u(pkh(g00, g01));
        gates[(size_t)(n0 + 1) * 64 + j2] = h2u(pkh(g10, g11));
        gates[(size_t)(n0 + 2) * 64 + j2] = h2u(pkh(g20, g21));
        gates[(size_t)(n0 + 3) * 64 + j2] = h2u(pkh(g30, g31));
    }
}

// ---- fused per-node pass: cosine sim + softmax + agg + gate apply -------
// One wave per node; 8 lanes/edge -> 8 edges in flight, depth-2 ring = 16
// X2h rows outstanding per wave (2x the R16 MLP). Lane covers 16 cols via
// two 128B-group coalesced uint4 loads (row[l8], row[l8+8]). Dot-reduce is
// 3 shuffle levels. f16 pk_fma accumulate; cross-oct merge in f32.
// cos in [-1,1] -> softmax needs no max subtraction (shift-invariant).
__global__ __launch_bounds__(256) void node_kernel(const float* __restrict__ X1,
                                                   const uint4* __restrict__ X2h,
                                                   const int* __restrict__ deg,
                                                   const int* __restrict__ cdst,
                                                   const float* __restrict__ inv2,
                                                   const unsigned* __restrict__ gates,
                                                   float* __restrict__ out) {
    int i = blockIdx.x * 4 + (threadIdx.x >> 6);  // 12500*4 == N1, no tail
    int lane = threadIdx.x & 63;
    int o = lane >> 3, l8 = lane & 7;  // oct o owns edges eb+o

    // gates row (epilogue use): uint4 k covers cols 8k..8k+7
    const uint4* grow = (const uint4*)(gates + (size_t)i * 64);
    uint4 gu0 = grow[l8], gu1 = grow[l8 + 8];

    // X1 row: lane covers cols 8*l8..+7 and 64+8*l8..+7
    const float4* p1 = (const float4*)(X1 + (size_t)i * D);
    float4 a0 = p1[2 * l8], a1 = p1[2 * l8 + 1];
    float4 a2 = p1[16 + 2 * l8], a3 = p1[17 + 2 * l8];
    float s = a0.x * a0.x + a0.y * a0.y + a0.z * a0.z + a0.w * a0.w
            + a1.x * a1.x + a1.y * a1.y + a1.z * a1.z + a1.w * a1.w
            + a2.x * a2.x + a2.y * a2.y + a2.z * a2.z + a2.w * a2.w
            + a3.x * a3.x + a3.y * a3.y + a3.z * a3.z + a3.w * a3.w;
    s += __shfl_xor(s, 1);
    s += __shfl_xor(s, 2);
    s += __shfl_xor(s, 4);   // each oct holds the full row -> intra-oct reduce
    float inv1 = 1.0f / fmaxf(sqrtf(s), EPSN);

    half2_t ah0 = pkh(a0.x, a0.y), ah1 = pkh(a0.z, a0.w);
    half2_t ah2 = pkh(a1.x, a1.y), ah3 = pkh(a1.z, a1.w);
    half2_t ah4 = pkh(a2.x, a2.y), ah5 = pkh(a2.z, a2.w);
    half2_t ah6 = pkh(a3.x, a3.y), ah7 = pkh(a3.z, a3.w);

    int dgi = deg[i];
    if (dgi > CAP) dgi = CAP;
    int e0 = i * CAP, e1 = e0 + dgi;

    float ssum = 0.0f;
    half2_t c0 = pkh(0.f, 0.f), c1 = c0, c2 = c0, c3 = c0;
    half2_t c4 = c0, c5 = c0, c6 = c0, c7 = c0;

    // depth-2 prefetch ring for this oct's edge stream
    uint4 b0lo = make_uint4(0u, 0u, 0u, 0u), b0hi = b0lo, b1lo = b0lo, b1hi = b0lo;
    float iv0 = 0.f, iv1 = 0.f;
    {
        int e = e0 + o;
        if (e < e1) {
            int dn = cdst[e];
            const uint4* r = X2h + (size_t)dn * 16;
            b0lo = r[l8]; b0hi = r[l8 + 8]; iv0 = inv2[dn];
        }
        if (e + 8 < e1) {
            int dn = cdst[e + 8];
            const uint4* r = X2h + (size_t)dn * 16;
            b1lo = r[l8]; b1hi = r[l8 + 8]; iv1 = inv2[dn];
        }
    }

    for (int eb = e0; eb < e1; eb += 8) {
        uint4 blo = b0lo, bhi = b0hi; float ivc = iv0;
        b0lo = b1lo; b0hi = b1hi; iv0 = iv1;
        int en = eb + 16 + o;
        if (en < e1) {
            int dn = cdst[en];
            const uint4* r = X2h + (size_t)dn * 16;
            b1lo = r[l8]; b1hi = r[l8 + 8]; iv1 = inv2[dn];
        }
        half2_t h0 = u2h(blo.x), h1 = u2h(blo.y), h2 = u2h(blo.z), h3 = u2h(blo.w);
        half2_t h4 = u2h(bhi.x), h5 = u2h(bhi.y), h6 = u2h(bhi.z), h7 = u2h(bhi.w);
        float pd = __builtin_amdgcn_fdot2(ah0, h0,
                   __builtin_amdgcn_fdot2(ah1, h1,
                   __builtin_amdgcn_fdot2(ah2, h2,
                   __builtin_amdgcn_fdot2(ah3, h3,
                   __builtin_amdgcn_fdot2(ah4, h4,
                   __builtin_amdgcn_fdot2(ah5, h5,
                   __builtin_amdgcn_fdot2(ah6, h6,
                   __builtin_amdgcn_fdot2(ah7, h7, 0.f, false),
                   false), false), false), false), false), false), false);
        pd += __shfl_xor(pd, 1);
        pd += __shfl_xor(pd, 2);
        pd += __shfl_xor(pd, 4);
        if (eb + o < e1) {
            float ex = __expf(pd * inv1 * ivc);
            ssum += ex;
            _Float16 exs = (_Float16)ex;
            half2_t exh; exh.x = exs; exh.y = exs;
            c0 += exh * h0; c1 += exh * h1; c2 += exh * h2; c3 += exh * h3;
            c4 += exh * h4; c5 += exh * h5; c6 += exh * h6; c7 += exh * h7;
        }
    }

    // widen to f32, merge the 8 oct states (butterfly over xor 8,16,32)
    float4 f0 = make_float4((float)c0.x, (float)c0.y, (float)c1.x, (float)c1.y);
    float4 f1 = make_float4((float)c2.x, (float)c2.y, (float)c3.x, (float)c3.y);
    float4 f2 = make_float4((float)c4.x, (float)c4.y, (float)c5.x, (float)c5.y);
    float4 f3 = make_float4((float)c6.x, (float)c6.y, (float)c7.x, (float)c7.y);
    #pragma unroll
    for (int off = 8; off <= 32; off <<= 1) {
        ssum += __shfl_xor(ssum, off);
        f0.x += __shfl_xor(f0.x, off); f0.y += __shfl_xor(f0.y, off);
        f0.z += __shfl_xor(f0.z, off); f0.w += __shfl_xor(f0.w, off);
        f1.x += __shfl_xor(f1.x, off); f1.y += __shfl_xor(f1.y, off);
        f1.z += __shfl_xor(f1.z, off); f1.w += __shfl_xor(f1.w, off);
        f2.x += __shfl_xor(f2.x, off); f2.y += __shfl_xor(f2.y, off);
        f2.z += __shfl_xor(f2.z, off); f2.w += __shfl_xor(f2.w, off);
        f3.x += __shfl_xor(f3.x, off); f3.y += __shfl_xor(f3.y, off);
        f3.z += __shfl_xor(f3.z, off); f3.w += __shfl_xor(f3.w, off);
    }
    float invs = (ssum > 0.f) ? (1.0f / ssum) : 0.f;  // empty segment -> 0
    if (o == 0) {
        half2_t g0 = u2h(gu0.x), g1 = u2h(gu0.y), g2 = u2h(gu0.z), g3 = u2h(gu0.w);
        half2_t g4 = u2h(gu1.x), g5 = u2h(gu1.y), g6 = u2h(gu1.z), g7 = u2h(gu1.w);
        float4* orow = (float4*)(out + (size_t)i * D);
        orow[2 * l8]      = make_float4(f0.x * invs * (float)g0.x,
                                        f0.y * invs * (float)g0.y,
                                        f0.z * invs * (float)g1.x,
                                        f0.w * invs * (float)g1.y);
        orow[2 * l8 + 1]  = make_float4(f1.x * invs * (float)g2.x,
                                        f1.y * invs * (float)g2.y,
                                        f1.z * invs * (float)g3.x,
                                        f1.w * invs * (float)g3.y);
        orow[16 + 2 * l8] = make_float4(f2.x * invs * (float)g4.x,
                                        f2.y * invs * (float)g4.y,
                                        f2.z * invs * (float)g5.x,
                                        f2.w * invs * (float)g5.y);
        orow[17 + 2 * l8] = make_float4(f3.x * invs * (float)g6.x,
                                        f3.y * invs * (float)g6.y,
                                        f3.z * invs * (float)g7.x,
                                        f3.w * invs * (float)g7.y);
    }
}

// ---- launch -------------------------------------------------------------

extern "C" void kernel_launch(void* const* d_in, const int* in_sizes, int n_in,
                              void* d_out, int out_size, void* d_ws, size_t ws_size,
                              hipStream_t stream) {
    const float* X1 = (const float*)d_in[0];
    const float* X2 = (const float*)d_in[1];
    const float* Xn = (const float*)d_in[2];
    const int*   ci = (const int*)d_in[3];
    const float* Wg = (const float*)d_in[4];
    float* out = (float*)d_out;

    const int* src = ci;
    const int* dst = ci + NE;

    char* ws = (char*)d_ws;
    int*      deg    = (int*)ws;      ws += N1 * sizeof(int);            // 200 KB
    ws += (16 - ((size_t)(ws - (char*)d_ws) & 15)) & 15;
    uint4*    X2h    = (uint4*)ws;    ws += (size_t)N2 * D * 2;          // 12.8 MB
    unsigned* gates  = (unsigned*)ws; ws += (size_t)N1 * 64 * 4;         // 12.8 MB
    int*      cdst   = (int*)ws;      ws += (size_t)N1 * CAP * 4;        // 12.8 MB
    float2*   WgT2g  = (float2*)ws;   ws += AD * 64 * sizeof(float2);
    float*    inv2   = (float*)ws;    ws += N2 * sizeof(float);

    conv_kernel<<<16 + CONV_BLKS, 256, 0, stream>>>(Wg, WgT2g, X2, X2h, inv2, deg);
    fill_kernel<<<FILL_BLKS, 256, 0, stream>>>(src, dst, deg, cdst);
    gate_kernel<<<GATE_BLKS, 256, 0, stream>>>(Xn, WgT2g, gates);
    node_kernel<<<N1 / 4, 256, 0, stream>>>(X1, X2h, deg, cdst, inv2, gates, out);
}

// Round 18
// 86.075 us; speedup vs baseline: 1.3726x; 1.3726x over previous
//
#include <hip/hip_runtime.h>
#include <math.h>

#define N1 50000
#define N2 50000
#define NE 640000
#define D 128
#define AD 64
#define CAP 64          // bucket capacity; Poisson(12.8) => P(deg>64) ~ 1e-17
#define EPSN 1e-8f

#define CONV_BLKS ((N2 + 31) / 32)   // 1563 (32 rows/block, 8 lanes/row)
#define FILL_BLKS (NE / 256)         // 2500
#define GATE_BLKS ((N1 + 63) / 64)   // 782

typedef _Float16 half2_t __attribute__((ext_vector_type(2)));

__device__ __forceinline__ half2_t pkh(float a, float b) {
    return __builtin_bit_cast(half2_t, __builtin_amdgcn_cvt_pkrtz(a, b));
}
__device__ __forceinline__ unsigned h2u(half2_t h) { return __builtin_bit_cast(unsigned, h); }
__device__ __forceinline__ half2_t u2h(unsigned u) { return __builtin_bit_cast(half2_t, u); }

// ---- conv: Wg transpose | X2->f16+inv2 (4 loads deep) | zero deg --------
// Pure streaming kernel (R15 lesson: keep scatters/atomics elsewhere).
__global__ __launch_bounds__(256) void conv_kernel(const float* __restrict__ Wg,
                                                   float2* __restrict__ WgT2g,
                                                   const float* __restrict__ X2,
                                                   uint4* __restrict__ X2h,
                                                   float* __restrict__ inv2,
                                                   int* __restrict__ deg) {
    int bid = blockIdx.x;
    int tid = threadIdx.x;
    if (bid < 16) {
        // WgT2g[k*64+j2] = (Wg[2j2][k], Wg[2j2+1][k]); Wg is [D][AD] row-major
        int t = bid * 256 + tid;
        int k = t >> 6, j2 = t & 63;
        WgT2g[t] = make_float2(Wg[(size_t)(2 * j2) * AD + k],
                               Wg[(size_t)(2 * j2 + 1) * AD + k]);
        return;
    }
    int rbase = (bid - 16) * 32;
    if (tid < 32 && rbase + tid < N1) deg[rbase + tid] = 0;  // replaces memset
    int row = rbase + (tid >> 3);
    if (row >= N2) return;
    int l8 = tid & 7;  // lane covers floats 16*l8 .. 16*l8+15
    const float4* pr = (const float4*)(X2 + (size_t)row * D) + l8 * 4;
    float4 v0 = pr[0], v1 = pr[1], v2 = pr[2], v3 = pr[3];
    float s = v0.x * v0.x + v0.y * v0.y + v0.z * v0.z + v0.w * v0.w
            + v1.x * v1.x + v1.y * v1.y + v1.z * v1.z + v1.w * v1.w
            + v2.x * v2.x + v2.y * v2.y + v2.z * v2.z + v2.w * v2.w
            + v3.x * v3.x + v3.y * v3.y + v3.z * v3.z + v3.w * v3.w;
    s += __shfl_xor(s, 4);
    s += __shfl_xor(s, 2);
    s += __shfl_xor(s, 1);
    if (l8 == 0) inv2[row] = 1.0f / fmaxf(sqrtf(s), EPSN);
    uint4 w0 = make_uint4(h2u(pkh(v0.x, v0.y)), h2u(pkh(v0.z, v0.w)),
                          h2u(pkh(v1.x, v1.y)), h2u(pkh(v1.z, v1.w)));
    uint4 w1 = make_uint4(h2u(pkh(v2.x, v2.y)), h2u(pkh(v2.z, v2.w)),
                          h2u(pkh(v3.x, v3.y)), h2u(pkh(v3.z, v3.w)));
    uint4* dstp = X2h + (size_t)row * 16 + l8 * 2;
    dstp[0] = w0;
    dstp[1] = w1;
}

// ---- gatefill: gate GEMM (blocks [0,GATE_BLKS)) | bucket fill (rest) ----
// Merged because they use DISJOINT resources: gate is LDS/FMA-bound with a
// small streaming write; fill is L2-atomic/scatter-bound. Concurrent block
// ranges overlap the two. Fill inherits the 32KB LDS reservation -> 5
// blocks/CU, fine for a latency-bound scatter.
__global__ __launch_bounds__(256) void gatefill_kernel(const float* __restrict__ Xn,
                                                       const float2* __restrict__ WgT2g,
                                                       unsigned* __restrict__ gates,
                                                       const int* __restrict__ src,
                                                       const int* __restrict__ dst,
                                                       int* __restrict__ deg,
                                                       int* __restrict__ cdst) {
    __shared__ float2 WgT2[AD * 64];  // 32 KB (gate branch only)
    int bid = blockIdx.x;
    if (bid < GATE_BLKS) {
        for (int t = threadIdx.x; t < AD * 64; t += 256) WgT2[t] = WgT2g[t];
        __syncthreads();

        int j2 = threadIdx.x & 63;  // lane: output columns (2*j2, 2*j2+1)
        int slot = __builtin_amdgcn_readfirstlane(threadIdx.x >> 6);
        int base = bid * 64 + slot * 16;

        #pragma unroll
        for (int g = 0; g < 4; ++g) {
            int n0 = base + g * 4;
            if (n0 >= N1) break;  // wave-uniform tail guard
            const float* x0 = Xn + (size_t)n0 * AD;
            const float* x1 = x0 + AD;
            const float* x2 = x0 + 2 * AD;
            const float* x3 = x0 + 3 * AD;
            float a00 = 0.f, a01 = 0.f, a10 = 0.f, a11 = 0.f;
            float a20 = 0.f, a21 = 0.f, a30 = 0.f, a31 = 0.f;
            #pragma unroll
            for (int k = 0; k < AD; ++k) {
                float2 w = WgT2[k * 64 + j2];
                float v0 = x0[k], v1 = x1[k], v2 = x2[k], v3 = x3[k];
                a00 += v0 * w.x; a01 += v0 * w.y;
                a10 += v1 * w.x; a11 += v1 * w.y;
                a20 += v2 * w.x; a21 += v2 * w.y;
                a30 += v3 * w.x; a31 += v3 * w.y;
            }
            float g00 = 1.0f / (1.0f + __expf(-a00));
            float g01 = 1.0f / (1.0f + __expf(-a01));
            float g10 = 1.0f / (1.0f + __expf(-a10));
            float g11 = 1.0f / (1.0f + __expf(-a11));
            float g20 = 1.0f / (1.0f + __expf(-a20));
            float g21 = 1.0f / (1.0f + __expf(-a21));
            float g30 = 1.0f / (1.0f + __expf(-a30));
            float g31 = 1.0f / (1.0f + __expf(-a31));
            gates[(size_t)n0 * 64 + j2]       = h2u(pkh(g00, g01));
            gates[(size_t)(n0 + 1) * 64 + j2] = h2u(pkh(g10, g11));
            gates[(size_t)(n0 + 2) * 64 + j2] = h2u(pkh(g20, g21));
            gates[(size_t)(n0 + 3) * 64 + j2] = h2u(pkh(g30, g31));
        }
        return;
    }
    // fill: 2500 blocks x 256 = 640000 exactly
    int e = (bid - GATE_BLKS) * 256 + threadIdx.x;
    int s = src[e];
    int p = atomicAdd(deg + s, 1);
    if (p < CAP) cdst[(size_t)s * CAP + p] = dst[e];
}

// ---- fused per-node pass (R16-proven): cos sim + softmax + agg + gate ---
// One wave per node; 4 edges in flight (16 lanes/edge, 8 f16 cols/lane),
// 2-deep prefetch ring (8 rows outstanding/wave). f16 pk_fma accumulate;
// cross-quarter merge in f32. cos in [-1,1] -> no max subtraction needed.
__global__ __launch_bounds__(256) void node_kernel(const float* __restrict__ X1,
                                                   const uint4* __restrict__ X2h,
                                                   const int* __restrict__ deg,
                                                   const int* __restrict__ cdst,
                                                   const float* __restrict__ inv2,
                                                   const unsigned* __restrict__ gates,
                                                   float* __restrict__ out) {
    int i = blockIdx.x * 4 + (threadIdx.x >> 6);  // 12500*4 == N1, no tail
    int lane = threadIdx.x & 63;
    int q = lane >> 4, l16 = lane & 15;  // quarter q owns edge eb+q

    // issue the gates row load early (used only in epilogue)
    uint4 gu = ((const uint4*)(gates + (size_t)i * 64))[l16];

    // lane covers cols 8*l16..8*l16+7 (all 4 quarters replicate the row)
    const float4* p1 = (const float4*)(X1 + (size_t)i * D);
    float4 a0 = p1[2 * l16], a1 = p1[2 * l16 + 1];
    float s = a0.x * a0.x + a0.y * a0.y + a0.z * a0.z + a0.w * a0.w
            + a1.x * a1.x + a1.y * a1.y + a1.z * a1.z + a1.w * a1.w;
    #pragma unroll
    for (int off = 8; off > 0; off >>= 1) s += __shfl_xor(s, off);
    float inv1 = 1.0f / fmaxf(sqrtf(s), EPSN);

    half2_t ah0 = pkh(a0.x, a0.y), ah1 = pkh(a0.z, a0.w);
    half2_t ah2 = pkh(a1.x, a1.y), ah3 = pkh(a1.z, a1.w);

    int dgi = deg[i];
    if (dgi > CAP) dgi = CAP;
    int e0 = i * CAP, e1 = e0 + dgi;

    float ssum = 0.0f;
    half2_t acch0 = pkh(0.f, 0.f), acch1 = acch0, acch2 = acch0, acch3 = acch0;

    // 2-deep prefetch ring for this quarter's edge stream
    uint4 b0 = make_uint4(0u, 0u, 0u, 0u), b1 = b0;
    float iv0 = 0.f, iv1 = 0.f;
    {
        int e = e0 + q;
        if (e < e1) { int dn = cdst[e]; b0 = X2h[(size_t)dn * 16 + l16]; iv0 = inv2[dn]; }
        if (e + 4 < e1) { int dn = cdst[e + 4]; b1 = X2h[(size_t)dn * 16 + l16]; iv1 = inv2[dn]; }
    }

    for (int eb = e0; eb < e1; eb += 4) {
        uint4 bc = b0; float ivc = iv0;
        b0 = b1; iv0 = iv1;
        int en = eb + 8 + q;
        if (en < e1) { int dn = cdst[en]; b1 = X2h[(size_t)dn * 16 + l16]; iv1 = inv2[dn]; }
        half2_t h0 = u2h(bc.x), h1 = u2h(bc.y), h2 = u2h(bc.z), h3 = u2h(bc.w);
        float pd = __builtin_amdgcn_fdot2(ah0, h0,
                   __builtin_amdgcn_fdot2(ah1, h1,
                   __builtin_amdgcn_fdot2(ah2, h2,
                   __builtin_amdgcn_fdot2(ah3, h3, 0.f, false), false), false), false);
        #pragma unroll
        for (int off = 8; off > 0; off >>= 1) pd += __shfl_xor(pd, off);
        if (eb + q < e1) {
            float ex = __expf(pd * inv1 * ivc);
            ssum += ex;
            _Float16 exs = (_Float16)ex;
            half2_t exh; exh.x = exs; exh.y = exs;
            acch0 += exh * h0;   // v_pk_fma_f16
            acch1 += exh * h1;
            acch2 += exh * h2;
            acch3 += exh * h3;
        }
    }

    // widen to f32, then merge the 4 quarter states
    float4 acc0 = make_float4((float)acch0.x, (float)acch0.y, (float)acch1.x, (float)acch1.y);
    float4 acc1 = make_float4((float)acch2.x, (float)acch2.y, (float)acch3.x, (float)acch3.y);
    #pragma unroll
    for (int off = 16; off <= 32; off <<= 1) {
        ssum   += __shfl_xor(ssum, off);
        acc0.x += __shfl_xor(acc0.x, off); acc0.y += __shfl_xor(acc0.y, off);
        acc0.z += __shfl_xor(acc0.z, off); acc0.w += __shfl_xor(acc0.w, off);
        acc1.x += __shfl_xor(acc1.x, off); acc1.y += __shfl_xor(acc1.y, off);
        acc1.z += __shfl_xor(acc1.z, off); acc1.w += __shfl_xor(acc1.w, off);
    }
    float invs = (ssum > 0.f) ? (1.0f / ssum) : 0.f;  // empty segment -> 0
    if (lane < 16) {
        half2_t g0 = u2h(gu.x), g1 = u2h(gu.y), g2 = u2h(gu.z), g3 = u2h(gu.w);
        float4* orow = (float4*)(out + (size_t)i * D);
        orow[2 * l16]     = make_float4(acc0.x * invs * (float)g0.x,
                                        acc0.y * invs * (float)g0.y,
                                        acc0.z * invs * (float)g1.x,
                                        acc0.w * invs * (float)g1.y);
        orow[2 * l16 + 1] = make_float4(acc1.x * invs * (float)g2.x,
                                        acc1.y * invs * (float)g2.y,
                                        acc1.z * invs * (float)g3.x,
                                        acc1.w * invs * (float)g3.y);
    }
}

// ---- launch -------------------------------------------------------------

extern "C" void kernel_launch(void* const* d_in, const int* in_sizes, int n_in,
                              void* d_out, int out_size, void* d_ws, size_t ws_size,
                              hipStream_t stream) {
    const float* X1 = (const float*)d_in[0];
    const float* X2 = (const float*)d_in[1];
    const float* Xn = (const float*)d_in[2];
    const int*   ci = (const int*)d_in[3];
    const float* Wg = (const float*)d_in[4];
    float* out = (float*)d_out;

    const int* src = ci;
    const int* dst = ci + NE;

    char* ws = (char*)d_ws;
    int*      deg    = (int*)ws;      ws += N1 * sizeof(int);            // 200 KB
    ws += (16 - ((size_t)(ws - (char*)d_ws) & 15)) & 15;
    uint4*    X2h    = (uint4*)ws;    ws += (size_t)N2 * D * 2;          // 12.8 MB
    unsigned* gates  = (unsigned*)ws; ws += (size_t)N1 * 64 * 4;         // 12.8 MB
    int*      cdst   = (int*)ws;      ws += (size_t)N1 * CAP * 4;        // 12.8 MB
    float2*   WgT2g  = (float2*)ws;   ws += AD * 64 * sizeof(float2);
    float*    inv2   = (float*)ws;    ws += N2 * sizeof(float);

    conv_kernel<<<16 + CONV_BLKS, 256, 0, stream>>>(Wg, WgT2g, X2, X2h, inv2, deg);
    gatefill_kernel<<<GATE_BLKS + FILL_BLKS, 256, 0, stream>>>(Xn, WgT2g, gates,
                                                               src, dst, deg, cdst);
    node_kernel<<<N1 / 4, 256, 0, stream>>>(X1, X2h, deg, cdst, inv2, gates, out);
}